// Round 1
// baseline (397.508 us; speedup 1.0000x reference)
//
#include <hip/hip_runtime.h>
#include <hip/hip_bf16.h>

// Problem constants (from reference): B=16, F=128, N=2048
#define B_ 16
#define F_ 128
#define N_ 2048
#define M_TOT (B_ * F_ * N_)   // 4,194,304 elements in emb_in

// ---------------------------------------------------------------------------
// Kernel 1: per-block partial sum / sum-of-squares over emb_in (float4 loads)
// grid = 1024, block = 256 -> each thread handles exactly 4 float4 (16 elems)
// ---------------------------------------------------------------------------
__global__ __launch_bounds__(256) void k_reduce(const float* __restrict__ emb,
                                                float* __restrict__ partials) {
    int tid = threadIdx.x;
    int gid = blockIdx.x * blockDim.x + tid;
    int stride = gridDim.x * blockDim.x;

    float s = 0.f, q = 0.f;
    const float4* e4 = (const float4*)emb;
    const int total4 = M_TOT / 4;  // 1,048,576
    for (int i = gid; i < total4; i += stride) {
        float4 v = e4[i];
        s += v.x + v.y + v.z + v.w;
        q += v.x * v.x + v.y * v.y + v.z * v.z + v.w * v.w;
    }

    // wave64 shuffle reduce
    #pragma unroll
    for (int off = 32; off > 0; off >>= 1) {
        s += __shfl_down(s, off);
        q += __shfl_down(q, off);
    }

    __shared__ float ls[4], lq[4];  // 256 threads = 4 waves
    int wave = tid >> 6;
    if ((tid & 63) == 0) { ls[wave] = s; lq[wave] = q; }
    __syncthreads();
    if (tid == 0) {
        float S = ls[0] + ls[1] + ls[2] + ls[3];
        float Q = lq[0] + lq[1] + lq[2] + lq[3];
        partials[2 * blockIdx.x]     = S;
        partials[2 * blockIdx.x + 1] = Q;
    }
}

// ---------------------------------------------------------------------------
// Kernel 2: single block reduces 1024 partial pairs -> inv_std scalar
// ---------------------------------------------------------------------------
__global__ __launch_bounds__(256) void k_finalize(const float* __restrict__ partials,
                                                  float* __restrict__ inv_std,
                                                  int nblk) {
    int tid = threadIdx.x;
    float s = 0.f, q = 0.f;
    for (int i = tid; i < nblk; i += blockDim.x) {
        s += partials[2 * i];
        q += partials[2 * i + 1];
    }
    #pragma unroll
    for (int off = 32; off > 0; off >>= 1) {
        s += __shfl_down(s, off);
        q += __shfl_down(q, off);
    }
    __shared__ float ls[4], lq[4];
    int wave = tid >> 6;
    if ((tid & 63) == 0) { ls[wave] = s; lq[wave] = q; }
    __syncthreads();
    if (tid == 0) {
        float S = ls[0] + ls[1] + ls[2] + ls[3];
        float Q = lq[0] + lq[1] + lq[2] + lq[3];
        float mean = S / (float)M_TOT;
        // unbiased variance over all elements (torch .std() default, ddof=1)
        float var = (Q - S * mean) / (float)(M_TOT - 1);
        inv_std[0] = rsqrtf(var);
    }
}

// ---------------------------------------------------------------------------
// Kernel 3: t[b,n] = inv_std * sum_f v[f]*emb[b,f,n] + 0.5*bias
// grid = 128, block = 256 -> one thread per (b,n); lanes hit consecutive n
// so each f-step is a fully coalesced 256B wave load.
// ---------------------------------------------------------------------------
__global__ __launch_bounds__(256) void k_dot(const float* __restrict__ emb,
                                             const float* __restrict__ v,
                                             const float* __restrict__ bias,
                                             const float* __restrict__ inv_std,
                                             float* __restrict__ t) {
    __shared__ float vs[F_];
    int tid = threadIdx.x;
    if (tid < F_) vs[tid] = v[tid];
    __syncthreads();

    int idx = blockIdx.x * blockDim.x + tid;  // 0 .. B_*N_-1
    int b = idx >> 11;        // / N_
    int n = idx & (N_ - 1);   // % N_
    const float* base = emb + (size_t)b * F_ * N_ + n;

    float acc = 0.f;
    #pragma unroll 8
    for (int f = 0; f < F_; ++f) {
        acc += vs[f] * base[(size_t)f * N_];
    }
    t[idx] = acc * inv_std[0] + 0.5f * bias[0];
}

// ---------------------------------------------------------------------------
// Kernel 4: out[b,i,j] = sigmoid(t[b,i] + t[b,j])   (bias already folded in t)
// One block per output row (b,i): 32768 blocks x 256 threads, 2 float4/thread.
// t row (8 KB) is L2-hot -> HBM traffic ~= pure 256 MiB write stream.
// ---------------------------------------------------------------------------
__device__ __forceinline__ float fast_sigmoid(float x) {
    float e = __expf(-x);
    return __builtin_amdgcn_rcpf(1.0f + e);
}

__global__ __launch_bounds__(256) void k_out(const float* __restrict__ t,
                                             float* __restrict__ out) {
    int row = blockIdx.x;           // b*N + i
    int b = row >> 11;              // / N_
    float si = t[row];

    const float4* t4 = (const float4*)(t + ((size_t)b << 11));
    float4* o4 = (float4*)(out + (size_t)row * N_);

    int tid = threadIdx.x;
    #pragma unroll
    for (int k = 0; k < 2; ++k) {
        int j4 = tid + k * 256;     // 0..511 float4 slots in the row
        float4 tj = t4[j4];
        float4 r;
        r.x = fast_sigmoid(si + tj.x);
        r.y = fast_sigmoid(si + tj.y);
        r.z = fast_sigmoid(si + tj.z);
        r.w = fast_sigmoid(si + tj.w);
        o4[j4] = r;
    }
}

// ---------------------------------------------------------------------------
// Launch
// ---------------------------------------------------------------------------
extern "C" void kernel_launch(void* const* d_in, const int* in_sizes, int n_in,
                              void* d_out, int out_size, void* d_ws, size_t ws_size,
                              hipStream_t stream) {
    // inputs in setup_inputs() order: adj_in (unused), emb_in, v, b
    const float* emb  = (const float*)d_in[1];
    const float* v    = (const float*)d_in[2];
    const float* bias = (const float*)d_in[3];
    float* out = (float*)d_out;

    // workspace layout (floats): [0..2047] partials, [2048] inv_std, [2304..] t
    float* wsf      = (float*)d_ws;
    float* partials = wsf;
    float* inv_std  = wsf + 2048;
    float* t        = wsf + 2304;   // B_*N_ = 32768 floats

    const int RB = 1024;  // reduction blocks

    k_reduce<<<RB, 256, 0, stream>>>(emb, partials);
    k_finalize<<<1, 256, 0, stream>>>(partials, inv_std, RB);
    k_dot<<<(B_ * N_) / 256, 256, 0, stream>>>(emb, v, bias, inv_std, t);
    k_out<<<B_ * N_, 256, 0, stream>>>(t, out);
}